// Round 8
// baseline (386.572 us; speedup 1.0000x reference)
//
#include <hip/hip_runtime.h>
#include <math.h>

#define T_TOK 8192
#define D_DIM 2048
#define E_EXP 64
#define CAP   256
#define NCHUNK 32           // T_TOK / 256
#define TEC   (134217728LL) // T*E*C
#define TE    (T_TOK * E_EXP)
#define KSPLIT 4
#define ROWBLK 64
#define N_GEMM_BLK 512      // (T/ROWBLK) * KSPLIT

// ---------------- K1: split-K logits GEMM (64x64 tile, 4x4/thread, prefetch) ----------------
__global__ __launch_bounds__(256) void k_gemm(const float* __restrict__ x,
                                              const float* __restrict__ wg,
                                              float* __restrict__ part) {
  __shared__ float xs[ROWBLK * 64];
  __shared__ float es[E_EXP * 64];
  const int tid = threadIdx.x;
  const int gb = blockIdx.x;
  const int rowblk = gb >> 2;
  const int kc = gb & 3;
  const int row0 = rowblk * ROWBLK;
  const int kbase = kc * 512;
  const int r = tid >> 2;   // 0..63 (staging row)
  const int q = tid & 3;    // granule quarter
  const float* xrow = x + (size_t)(row0 + r) * D_DIM + kbase;
  const float* erow = wg + (size_t)r * D_DIM + kbase;
  float4 ax[4], bx[4];

#define ISSUE(t)                                                              \
  {                                                                           \
    const int kk = (t) * 64;                                                  \
    _Pragma("unroll") for (int i = 0; i < 4; ++i) {                           \
      ax[i] = *reinterpret_cast<const float4*>(xrow + kk + (q + 4 * i) * 4);  \
      bx[i] = *reinterpret_cast<const float4*>(erow + kk + (q + 4 * i) * 4);  \
    }                                                                         \
  }
#define WRITE()                                                               \
  {                                                                           \
    _Pragma("unroll") for (int i = 0; i < 4; ++i) {                           \
      const int gi = q + 4 * i;                                               \
      const int pos = gi ^ (r & 7);                                           \
      *reinterpret_cast<float4*>(&xs[(r * 16 + pos) * 4]) = ax[i];            \
      *reinterpret_cast<float4*>(&es[(r * 16 + pos) * 4]) = bx[i];            \
    }                                                                         \
  }

  float acc[4][4] = {{0.f}};
  const int tr = tid & 15;   // output rows tr+16j
  const int tc = tid >> 4;   // output cols tc+16j
  ISSUE(0);
  WRITE();
  __syncthreads();
  for (int t = 0; t < 8; ++t) {
    if (t < 7) ISSUE(t + 1);
#pragma unroll
    for (int g = 0; g < 16; ++g) {
      float4 a[4], b[4];
#pragma unroll
      for (int j = 0; j < 4; ++j) {
        const int ra = tr + 16 * j;
        const int rb = tc + 16 * j;
        a[j] = *reinterpret_cast<const float4*>(&xs[(ra * 16 + (g ^ (ra & 7))) * 4]);
        b[j] = *reinterpret_cast<const float4*>(&es[(rb * 16 + (g ^ (rb & 7))) * 4]);
      }
#pragma unroll
      for (int jr = 0; jr < 4; ++jr)
#pragma unroll
        for (int jc = 0; jc < 4; ++jc) {
          acc[jr][jc] = fmaf(a[jr].x, b[jc].x, acc[jr][jc]);
          acc[jr][jc] = fmaf(a[jr].y, b[jc].y, acc[jr][jc]);
          acc[jr][jc] = fmaf(a[jr].z, b[jc].z, acc[jr][jc]);
          acc[jr][jc] = fmaf(a[jr].w, b[jc].w, acc[jr][jc]);
        }
    }
    __syncthreads();
    if (t < 7) {
      WRITE();
      __syncthreads();
    }
  }
  float* pbase = part + (size_t)kc * TE;
#pragma unroll
  for (int jr = 0; jr < 4; ++jr)
#pragma unroll
    for (int jc = 0; jc < 4; ++jc)
      pbase[(size_t)(row0 + tr + 16 * jr) * E_EXP + tc + 16 * jc] = acc[jr][jc];
#undef ISSUE
#undef WRITE
}

// ---------------- K2: per-row softmax + top1 + gumbel-top2 ----------------
// grid 256 x 256 threads (4 waves); wave w of block b handles tokens
// (b*4+w) + i*1024. Sums the 4 split-K partials in fixed order (deterministic).
__global__ __launch_bounds__(256) void k_gate(const float* __restrict__ part,
                                              const float* __restrict__ gumbel,
                                              float* __restrict__ colpart,
                                              int* __restrict__ idx1,
                                              int* __restrict__ idx2,
                                              float* __restrict__ g1v,
                                              float* __restrict__ g2v) {
  const int lane = threadIdx.x & 63;
  const int wave = threadIdx.x >> 6;
  const int gwave = blockIdx.x * 4 + wave;  // 0..1023
  float colacc = 0.f;
  for (int i = 0; i < 8; ++i) {
    const int t = gwave + i * 1024;
    const int o = t * 64 + lane;
    const float L = (part[o] + part[TE + o]) + (part[2 * TE + o] + part[3 * TE + o]);
    // row max
    float m = L;
#pragma unroll
    for (int off = 32; off; off >>= 1) m = fmaxf(m, __shfl_xor(m, off));
    const float e = expf(L - m);
    float s = e;
#pragma unroll
    for (int off = 32; off; off >>= 1) s += __shfl_xor(s, off);
    const float g = e / s;
    colacc += g;
    // argmax1 over gates, first-max semantics (ties -> lowest index)
    float v = g; int ix = lane;
#pragma unroll
    for (int off = 32; off; off >>= 1) {
      float v2 = __shfl_xor(v, off); int i2 = __shfl_xor(ix, off);
      if (v2 > v || (v2 == v && i2 < ix)) { v = v2; ix = i2; }
    }
    const int i1 = ix;
    const float gate1 = __shfl(g, i1);
    // argmax2 over noised logits, expert i1 masked out
    float nz = L + gumbel[o];
    if (lane == i1) nz = -INFINITY;
    float v2v = nz; int ix2 = lane;
#pragma unroll
    for (int off = 32; off; off >>= 1) {
      float v2 = __shfl_xor(v2v, off); int j2 = __shfl_xor(ix2, off);
      if (v2 > v2v || (v2 == v2v && j2 < ix2)) { v2v = v2; ix2 = j2; }
    }
    const int i2x = ix2;
    const float gate2 = __shfl(g, i2x);
    if (lane == 0) { idx1[t] = i1; idx2[t] = i2x; g1v[t] = gate1; g2v[t] = gate2; }
  }
  __shared__ float cs[4][64];
  cs[wave][lane] = colacc;
  __syncthreads();
  if (wave == 0) {
    float ssum = cs[0][lane] + cs[1][lane] + cs[2][lane] + cs[3][lane];
    colpart[blockIdx.x * 64 + lane] = ssum;
  }
}

// ---------------- K3: local ranks + chunk histograms ----------------
// 32 blocks x 256 threads; chunk = 256 tokens.
__global__ __launch_bounds__(256) void k_rank(const int* __restrict__ idx1,
                                              const int* __restrict__ idx2,
                                              int* __restrict__ rank1,
                                              int* __restrict__ rank2,
                                              int* __restrict__ hist1,
                                              int* __restrict__ hist2) {
  __shared__ int s1[256], s2[256];
  __shared__ int h1[64], h2[64];
  const int tid = threadIdx.x;
  const int base = blockIdx.x * 256;
  if (tid < 64) { h1[tid] = 0; h2[tid] = 0; }
  s1[tid] = idx1[base + tid];
  s2[tid] = idx2[base + tid];
  __syncthreads();
  const int my1 = s1[tid], my2 = s2[tid];
  int r1 = 0, r2 = 0;
  for (int j = 0; j < 256; ++j) {
    r1 += (j < tid && s1[j] == my1);
    r2 += (j < tid && s2[j] == my2);
  }
  atomicAdd(&h1[my1], 1);
  atomicAdd(&h2[my2], 1);
  rank1[base + tid] = r1;
  rank2[base + tid] = r2;
  __syncthreads();
  if (tid < 64) {
    hist1[blockIdx.x * 64 + tid] = h1[tid];
    hist2[blockIdx.x * 64 + tid] = h2[tid];
  }
}

// ---------------- K4: chunk-prefix offsets + l_aux ----------------
__global__ __launch_bounds__(64) void k_prefix(const int* __restrict__ hist1,
                                               const int* __restrict__ hist2,
                                               const float* __restrict__ colpart,
                                               int* __restrict__ offs1,
                                               int* __restrict__ offs2,
                                               float* __restrict__ dout) {
  const int e = threadIdx.x;
  int run = 0;
  for (int c = 0; c < NCHUNK; ++c) { offs1[c * 64 + e] = run; run += hist1[c * 64 + e]; }
  const int total1 = run;
  int run2 = total1;  // locations2 offset includes sum(mask1, axis=0)
  for (int c = 0; c < NCHUNK; ++c) { offs2[c * 64 + e] = run2; run2 += hist2[c * 64 + e]; }
  float csum = 0.f;
  for (int b = 0; b < 256; ++b) csum += colpart[b * 64 + e];
  const float me = csum / (float)T_TOK;
  const float ce = (float)total1 / (float)T_TOK;
  float val = me * ce;
#pragma unroll
  for (int o = 32; o; o >>= 1) val += __shfl_xor(val, o);
  if (e == 0) dout[0] = val * (float)E_EXP;  // mean(me*ce)*E*E = sum*E
}

// ---------------- K5: sparse scatter of combine weights + dispatch ----------------
__global__ __launch_bounds__(256) void k_scatter(const int* __restrict__ idx1,
                                                 const int* __restrict__ idx2,
                                                 const float* __restrict__ g1v,
                                                 const float* __restrict__ g2v,
                                                 const int* __restrict__ rank1,
                                                 const int* __restrict__ rank2,
                                                 const int* __restrict__ offs1,
                                                 const int* __restrict__ offs2,
                                                 float* __restrict__ dout) {
  const int t = blockIdx.x * 256 + threadIdx.x;
  const int c = t >> 8;
  const int e1 = idx1[t], e2 = idx2[t];
  const int loc1 = offs1[c * 64 + e1] + rank1[t];
  const int loc2 = offs2[c * 64 + e2] + rank2[t];
  const bool k1 = loc1 < CAP;
  const bool k2 = loc2 < CAP;
  const float a = k1 ? g1v[t] : 0.f;
  const float b = k2 ? g2v[t] : 0.f;
  const float denom = fmaxf(a + b, 1.1920929e-7f);  // FLT_EPSILON
  if (k1) {
    const long long o = 1LL + ((long long)t * 64 + e1) * 256 + loc1;
    dout[o] = a / denom;
    dout[o + TEC] = 1.0f;
  }
  if (k2) {
    const long long o = 1LL + ((long long)t * 64 + e2) * 256 + loc2;
    dout[o] = b / denom;
    dout[o + TEC] = 1.0f;
  }
}

extern "C" void kernel_launch(void* const* d_in, const int* in_sizes, int n_in,
                              void* d_out, int out_size, void* d_ws, size_t ws_size,
                              hipStream_t stream) {
  const float* x = (const float*)d_in[0];
  const float* wg = (const float*)d_in[1];
  const float* gumbel = (const float*)d_in[2];
  float* dout = (float*)d_out;

  // workspace layout (aligned chunks)
  char* p = (char*)d_ws;
  float* part = (float*)p;              p += (size_t)KSPLIT * TE * 4;     // 8 MB
  float* colpart = (float*)p;           p += 256 * 64 * 4;                // 64 KB
  float* g1v = (float*)p;               p += T_TOK * 4;
  float* g2v = (float*)p;               p += T_TOK * 4;
  int* idx1 = (int*)p;                  p += T_TOK * 4;
  int* idx2 = (int*)p;                  p += T_TOK * 4;
  int* rank1 = (int*)p;                 p += T_TOK * 4;
  int* rank2 = (int*)p;                 p += T_TOK * 4;
  int* hist1 = (int*)p;                 p += NCHUNK * 64 * 4;
  int* hist2 = (int*)p;                 p += NCHUNK * 64 * 4;
  int* offs1 = (int*)p;                 p += NCHUNK * 64 * 4;
  int* offs2 = (int*)p;                 p += NCHUNK * 64 * 4;

  // zero-fill the (sparse) 1.07 GB output — the structural floor of this op
  hipMemsetAsync(d_out, 0, (size_t)out_size * sizeof(float), stream);

  k_gemm<<<N_GEMM_BLK, 256, 0, stream>>>(x, wg, part);
  k_gate<<<256, 256, 0, stream>>>(part, gumbel, colpart, idx1, idx2, g1v, g2v);
  k_rank<<<NCHUNK, 256, 0, stream>>>(idx1, idx2, rank1, rank2, hist1, hist2);
  k_prefix<<<1, 64, 0, stream>>>(hist1, hist2, colpart, offs1, offs2, dout);
  k_scatter<<<NCHUNK, 256, 0, stream>>>(idx1, idx2, g1v, g2v, rank1, rank2,
                                        offs1, offs2, dout);
}

// Round 9
// 266.691 us; speedup vs baseline: 1.4495x; 1.4495x over previous
//
#include <hip/hip_runtime.h>
#include <math.h>

#define T_TOK 8192
#define D_DIM 2048
#define E_EXP 64
#define CAP   256
#define NCHUNK 32           // T_TOK / 256
#define TEC   (134217728LL) // T*E*C
#define TE    (T_TOK * E_EXP)
#define KSPLIT 2

__device__ __forceinline__ int swz(int r) { return (r & 7) ^ ((r >> 3) & 7); }

// ---------------- K1: split-K x2 logits GEMM, R7 inner loop verbatim ----------------
// 512 blocks: rowblk = bid>>1 (32 rows), kc = bid&1 (K in [kc*1024, kc*1024+1024)).
__global__ __launch_bounds__(256) void k_gemm(const float* __restrict__ x,
                                              const float* __restrict__ wg,
                                              float* __restrict__ part) {
  __shared__ float xs[32 * 64];
  __shared__ float ws[64 * 64];
  const int tid = threadIdx.x;
  const int row0 = (blockIdx.x >> 1) * 32;
  const int kc = blockIdx.x & 1;
  const int kbase = kc * 1024;
  const int rr = tid >> 4;   // 0..15 -> rows rr, rr+16
  const int cc = tid & 15;   // cols cc*4..cc*4+3
  const int sA0 = swz(rr), sA1 = swz(rr + 16);
  const int sB0 = swz(cc * 4 + 0), sB1 = swz(cc * 4 + 1);
  const int sB2 = swz(cc * 4 + 2), sB3 = swz(cc * 4 + 3);
  float acc[2][4] = {{0.f, 0.f, 0.f, 0.f}, {0.f, 0.f, 0.f, 0.f}};
  for (int k0 = kbase; k0 < kbase + 1024; k0 += 64) {
#pragma unroll
    for (int i = 0; i < 2; ++i) {
      const int f = tid + i * 256;
      const int r = f >> 4, g = f & 15;
      const float4 v = *reinterpret_cast<const float4*>(
          &x[(size_t)(row0 + r) * D_DIM + k0 + g * 4]);
      *reinterpret_cast<float4*>(&xs[r * 64 + ((g ^ swz(r)) << 2)]) = v;
    }
#pragma unroll
    for (int i = 0; i < 4; ++i) {
      const int f = tid + i * 256;
      const int r = f >> 4, g = f & 15;
      const float4 v = *reinterpret_cast<const float4*>(
          &wg[(size_t)r * D_DIM + k0 + g * 4]);
      *reinterpret_cast<float4*>(&ws[r * 64 + ((g ^ swz(r)) << 2)]) = v;
    }
    __syncthreads();
#pragma unroll
    for (int g = 0; g < 16; ++g) {
      const float4 a0 = *reinterpret_cast<const float4*>(&xs[rr * 64 + ((g ^ sA0) << 2)]);
      const float4 a1 = *reinterpret_cast<const float4*>(&xs[(rr + 16) * 64 + ((g ^ sA1) << 2)]);
      const float4 b0 = *reinterpret_cast<const float4*>(&ws[(cc * 4 + 0) * 64 + ((g ^ sB0) << 2)]);
      const float4 b1 = *reinterpret_cast<const float4*>(&ws[(cc * 4 + 1) * 64 + ((g ^ sB1) << 2)]);
      const float4 b2 = *reinterpret_cast<const float4*>(&ws[(cc * 4 + 2) * 64 + ((g ^ sB2) << 2)]);
      const float4 b3 = *reinterpret_cast<const float4*>(&ws[(cc * 4 + 3) * 64 + ((g ^ sB3) << 2)]);
      acc[0][0] = fmaf(a0.x, b0.x, acc[0][0]); acc[0][0] = fmaf(a0.y, b0.y, acc[0][0]);
      acc[0][0] = fmaf(a0.z, b0.z, acc[0][0]); acc[0][0] = fmaf(a0.w, b0.w, acc[0][0]);
      acc[0][1] = fmaf(a0.x, b1.x, acc[0][1]); acc[0][1] = fmaf(a0.y, b1.y, acc[0][1]);
      acc[0][1] = fmaf(a0.z, b1.z, acc[0][1]); acc[0][1] = fmaf(a0.w, b1.w, acc[0][1]);
      acc[0][2] = fmaf(a0.x, b2.x, acc[0][2]); acc[0][2] = fmaf(a0.y, b2.y, acc[0][2]);
      acc[0][2] = fmaf(a0.z, b2.z, acc[0][2]); acc[0][2] = fmaf(a0.w, b2.w, acc[0][2]);
      acc[0][3] = fmaf(a0.x, b3.x, acc[0][3]); acc[0][3] = fmaf(a0.y, b3.y, acc[0][3]);
      acc[0][3] = fmaf(a0.z, b3.z, acc[0][3]); acc[0][3] = fmaf(a0.w, b3.w, acc[0][3]);
      acc[1][0] = fmaf(a1.x, b0.x, acc[1][0]); acc[1][0] = fmaf(a1.y, b0.y, acc[1][0]);
      acc[1][0] = fmaf(a1.z, b0.z, acc[1][0]); acc[1][0] = fmaf(a1.w, b0.w, acc[1][0]);
      acc[1][1] = fmaf(a1.x, b1.x, acc[1][1]); acc[1][1] = fmaf(a1.y, b1.y, acc[1][1]);
      acc[1][1] = fmaf(a1.z, b1.z, acc[1][1]); acc[1][1] = fmaf(a1.w, b1.w, acc[1][1]);
      acc[1][2] = fmaf(a1.x, b2.x, acc[1][2]); acc[1][2] = fmaf(a1.y, b2.y, acc[1][2]);
      acc[1][2] = fmaf(a1.z, b2.z, acc[1][2]); acc[1][2] = fmaf(a1.w, b2.w, acc[1][2]);
      acc[1][3] = fmaf(a1.x, b3.x, acc[1][3]); acc[1][3] = fmaf(a1.y, b3.y, acc[1][3]);
      acc[1][3] = fmaf(a1.z, b3.z, acc[1][3]); acc[1][3] = fmaf(a1.w, b3.w, acc[1][3]);
    }
    __syncthreads();
  }
  const float4 o0 = make_float4(acc[0][0], acc[0][1], acc[0][2], acc[0][3]);
  const float4 o1 = make_float4(acc[1][0], acc[1][1], acc[1][2], acc[1][3]);
  float* pbase = part + (size_t)kc * TE;
  *reinterpret_cast<float4*>(&pbase[(size_t)(row0 + rr) * E_EXP + cc * 4]) = o0;
  *reinterpret_cast<float4*>(&pbase[(size_t)(row0 + rr + 16) * E_EXP + cc * 4]) = o1;
}

// ---------------- K2: per-row softmax + top1 + gumbel-top2 ----------------
// grid 256 x 256 threads (4 waves). Sums the 2 split-K partials in fixed order.
__global__ __launch_bounds__(256) void k_gate(const float* __restrict__ part,
                                              const float* __restrict__ gumbel,
                                              float* __restrict__ colpart,
                                              int* __restrict__ idx1,
                                              int* __restrict__ idx2,
                                              float* __restrict__ g1v,
                                              float* __restrict__ g2v) {
  const int lane = threadIdx.x & 63;
  const int wave = threadIdx.x >> 6;
  const int gwave = blockIdx.x * 4 + wave;  // 0..1023
  float colacc = 0.f;
  for (int i = 0; i < 8; ++i) {
    const int t = gwave + i * 1024;
    const int o = t * 64 + lane;
    const float L = part[o] + part[TE + o];
    // row max
    float m = L;
#pragma unroll
    for (int off = 32; off; off >>= 1) m = fmaxf(m, __shfl_xor(m, off));
    const float e = expf(L - m);
    float s = e;
#pragma unroll
    for (int off = 32; off; off >>= 1) s += __shfl_xor(s, off);
    const float g = e / s;
    colacc += g;
    // argmax1 over gates, first-max semantics (ties -> lowest index)
    float v = g; int ix = lane;
#pragma unroll
    for (int off = 32; off; off >>= 1) {
      float v2 = __shfl_xor(v, off); int i2 = __shfl_xor(ix, off);
      if (v2 > v || (v2 == v && i2 < ix)) { v = v2; ix = i2; }
    }
    const int i1 = ix;
    const float gate1 = __shfl(g, i1);
    // argmax2 over noised logits, expert i1 masked out
    float nz = L + gumbel[o];
    if (lane == i1) nz = -INFINITY;
    float v2v = nz; int ix2 = lane;
#pragma unroll
    for (int off = 32; off; off >>= 1) {
      float v2 = __shfl_xor(v2v, off); int j2 = __shfl_xor(ix2, off);
      if (v2 > v2v || (v2 == v2v && j2 < ix2)) { v2v = v2; ix2 = j2; }
    }
    const int i2x = ix2;
    const float gate2 = __shfl(g, i2x);
    if (lane == 0) { idx1[t] = i1; idx2[t] = i2x; g1v[t] = gate1; g2v[t] = gate2; }
  }
  __shared__ float cs[4][64];
  cs[wave][lane] = colacc;
  __syncthreads();
  if (wave == 0) {
    float ssum = cs[0][lane] + cs[1][lane] + cs[2][lane] + cs[3][lane];
    colpart[blockIdx.x * 64 + lane] = ssum;
  }
}

// ---------------- K3: local ranks + chunk histograms ----------------
__global__ __launch_bounds__(256) void k_rank(const int* __restrict__ idx1,
                                              const int* __restrict__ idx2,
                                              int* __restrict__ rank1,
                                              int* __restrict__ rank2,
                                              int* __restrict__ hist1,
                                              int* __restrict__ hist2) {
  __shared__ int s1[256], s2[256];
  __shared__ int h1[64], h2[64];
  const int tid = threadIdx.x;
  const int base = blockIdx.x * 256;
  if (tid < 64) { h1[tid] = 0; h2[tid] = 0; }
  s1[tid] = idx1[base + tid];
  s2[tid] = idx2[base + tid];
  __syncthreads();
  const int my1 = s1[tid], my2 = s2[tid];
  int r1 = 0, r2 = 0;
  for (int j = 0; j < 256; ++j) {
    r1 += (j < tid && s1[j] == my1);
    r2 += (j < tid && s2[j] == my2);
  }
  atomicAdd(&h1[my1], 1);
  atomicAdd(&h2[my2], 1);
  rank1[base + tid] = r1;
  rank2[base + tid] = r2;
  __syncthreads();
  if (tid < 64) {
    hist1[blockIdx.x * 64 + tid] = h1[tid];
    hist2[blockIdx.x * 64 + tid] = h2[tid];
  }
}

// ---------------- K4: chunk-prefix offsets + l_aux ----------------
__global__ __launch_bounds__(64) void k_prefix(const int* __restrict__ hist1,
                                               const int* __restrict__ hist2,
                                               const float* __restrict__ colpart,
                                               int* __restrict__ offs1,
                                               int* __restrict__ offs2,
                                               float* __restrict__ dout) {
  const int e = threadIdx.x;
  int run = 0;
  for (int c = 0; c < NCHUNK; ++c) { offs1[c * 64 + e] = run; run += hist1[c * 64 + e]; }
  const int total1 = run;
  int run2 = total1;  // locations2 offset includes sum(mask1, axis=0)
  for (int c = 0; c < NCHUNK; ++c) { offs2[c * 64 + e] = run2; run2 += hist2[c * 64 + e]; }
  float csum = 0.f;
  for (int b = 0; b < 256; ++b) csum += colpart[b * 64 + e];
  const float me = csum / (float)T_TOK;
  const float ce = (float)total1 / (float)T_TOK;
  float val = me * ce;
#pragma unroll
  for (int o = 32; o; o >>= 1) val += __shfl_xor(val, o);
  if (e == 0) dout[0] = val * (float)E_EXP;  // mean(me*ce)*E*E = sum*E
}

// ---------------- K5: sparse scatter of combine weights + dispatch ----------------
__global__ __launch_bounds__(256) void k_scatter(const int* __restrict__ idx1,
                                                 const int* __restrict__ idx2,
                                                 const float* __restrict__ g1v,
                                                 const float* __restrict__ g2v,
                                                 const int* __restrict__ rank1,
                                                 const int* __restrict__ rank2,
                                                 const int* __restrict__ offs1,
                                                 const int* __restrict__ offs2,
                                                 float* __restrict__ dout) {
  const int t = blockIdx.x * 256 + threadIdx.x;
  const int c = t >> 8;
  const int e1 = idx1[t], e2 = idx2[t];
  const int loc1 = offs1[c * 64 + e1] + rank1[t];
  const int loc2 = offs2[c * 64 + e2] + rank2[t];
  const bool k1 = loc1 < CAP;
  const bool k2 = loc2 < CAP;
  const float a = k1 ? g1v[t] : 0.f;
  const float b = k2 ? g2v[t] : 0.f;
  const float denom = fmaxf(a + b, 1.1920929e-7f);  // FLT_EPSILON
  if (k1) {
    const long long o = 1LL + ((long long)t * 64 + e1) * 256 + loc1;
    dout[o] = a / denom;
    dout[o + TEC] = 1.0f;
  }
  if (k2) {
    const long long o = 1LL + ((long long)t * 64 + e2) * 256 + loc2;
    dout[o] = b / denom;
    dout[o + TEC] = 1.0f;
  }
}

extern "C" void kernel_launch(void* const* d_in, const int* in_sizes, int n_in,
                              void* d_out, int out_size, void* d_ws, size_t ws_size,
                              hipStream_t stream) {
  const float* x = (const float*)d_in[0];
  const float* wg = (const float*)d_in[1];
  const float* gumbel = (const float*)d_in[2];
  float* dout = (float*)d_out;

  // workspace layout (aligned chunks)
  char* p = (char*)d_ws;
  float* part = (float*)p;              p += (size_t)KSPLIT * TE * 4;     // 4 MB
  float* colpart = (float*)p;           p += 256 * 64 * 4;                // 64 KB
  float* g1v = (float*)p;               p += T_TOK * 4;
  float* g2v = (float*)p;               p += T_TOK * 4;
  int* idx1 = (int*)p;                  p += T_TOK * 4;
  int* idx2 = (int*)p;                  p += T_TOK * 4;
  int* rank1 = (int*)p;                 p += T_TOK * 4;
  int* rank2 = (int*)p;                 p += T_TOK * 4;
  int* hist1 = (int*)p;                 p += NCHUNK * 64 * 4;
  int* hist2 = (int*)p;                 p += NCHUNK * 64 * 4;
  int* offs1 = (int*)p;                 p += NCHUNK * 64 * 4;
  int* offs2 = (int*)p;                 p += NCHUNK * 64 * 4;

  // zero-fill the (sparse) 1.07 GB output — the structural floor of this op
  hipMemsetAsync(d_out, 0, (size_t)out_size * sizeof(float), stream);

  k_gemm<<<(T_TOK / 32) * KSPLIT, 256, 0, stream>>>(x, wg, part);
  k_gate<<<256, 256, 0, stream>>>(part, gumbel, colpart, idx1, idx2, g1v, g2v);
  k_rank<<<NCHUNK, 256, 0, stream>>>(idx1, idx2, rank1, rank2, hist1, hist2);
  k_prefix<<<1, 64, 0, stream>>>(hist1, hist2, colpart, offs1, offs2, dout);
  k_scatter<<<NCHUNK, 256, 0, stream>>>(idx1, idx2, g1v, g2v, rank1, rank2,
                                        offs1, offs2, dout);
}

// Round 10
// 263.157 us; speedup vs baseline: 1.4690x; 1.0134x over previous
//
#include <hip/hip_runtime.h>
#include <math.h>

#define T_TOK 8192
#define D_DIM 2048
#define E_EXP 64
#define CAP   256
#define NCHUNK 32           // T_TOK / 256
#define TEC   (134217728LL) // T*E*C
#define TE    (T_TOK * E_EXP)
#define KSPLIT 4
#define KLEN   (D_DIM / KSPLIT)

__device__ __forceinline__ int swz(int r) { return (r & 7) ^ ((r >> 3) & 7); }

// ---------------- K1: split-K x4 logits GEMM, R7/R9 inner loop verbatim ----------------
// 1024 blocks: rowblk = bid>>2 (32 rows), kc = bid&3 (K in [kc*512, kc*512+512)).
__global__ __launch_bounds__(256) void k_gemm(const float* __restrict__ x,
                                              const float* __restrict__ wg,
                                              float* __restrict__ part) {
  __shared__ float xs[32 * 64];
  __shared__ float ws[64 * 64];
  const int tid = threadIdx.x;
  const int row0 = (blockIdx.x >> 2) * 32;
  const int kc = blockIdx.x & 3;
  const int kbase = kc * KLEN;
  const int rr = tid >> 4;   // 0..15 -> rows rr, rr+16
  const int cc = tid & 15;   // cols cc*4..cc*4+3
  const int sA0 = swz(rr), sA1 = swz(rr + 16);
  const int sB0 = swz(cc * 4 + 0), sB1 = swz(cc * 4 + 1);
  const int sB2 = swz(cc * 4 + 2), sB3 = swz(cc * 4 + 3);
  float acc[2][4] = {{0.f, 0.f, 0.f, 0.f}, {0.f, 0.f, 0.f, 0.f}};
  for (int k0 = kbase; k0 < kbase + KLEN; k0 += 64) {
#pragma unroll
    for (int i = 0; i < 2; ++i) {
      const int f = tid + i * 256;
      const int r = f >> 4, g = f & 15;
      const float4 v = *reinterpret_cast<const float4*>(
          &x[(size_t)(row0 + r) * D_DIM + k0 + g * 4]);
      *reinterpret_cast<float4*>(&xs[r * 64 + ((g ^ swz(r)) << 2)]) = v;
    }
#pragma unroll
    for (int i = 0; i < 4; ++i) {
      const int f = tid + i * 256;
      const int r = f >> 4, g = f & 15;
      const float4 v = *reinterpret_cast<const float4*>(
          &wg[(size_t)r * D_DIM + k0 + g * 4]);
      *reinterpret_cast<float4*>(&ws[r * 64 + ((g ^ swz(r)) << 2)]) = v;
    }
    __syncthreads();
#pragma unroll
    for (int g = 0; g < 16; ++g) {
      const float4 a0 = *reinterpret_cast<const float4*>(&xs[rr * 64 + ((g ^ sA0) << 2)]);
      const float4 a1 = *reinterpret_cast<const float4*>(&xs[(rr + 16) * 64 + ((g ^ sA1) << 2)]);
      const float4 b0 = *reinterpret_cast<const float4*>(&ws[(cc * 4 + 0) * 64 + ((g ^ sB0) << 2)]);
      const float4 b1 = *reinterpret_cast<const float4*>(&ws[(cc * 4 + 1) * 64 + ((g ^ sB1) << 2)]);
      const float4 b2 = *reinterpret_cast<const float4*>(&ws[(cc * 4 + 2) * 64 + ((g ^ sB2) << 2)]);
      const float4 b3 = *reinterpret_cast<const float4*>(&ws[(cc * 4 + 3) * 64 + ((g ^ sB3) << 2)]);
      acc[0][0] = fmaf(a0.x, b0.x, acc[0][0]); acc[0][0] = fmaf(a0.y, b0.y, acc[0][0]);
      acc[0][0] = fmaf(a0.z, b0.z, acc[0][0]); acc[0][0] = fmaf(a0.w, b0.w, acc[0][0]);
      acc[0][1] = fmaf(a0.x, b1.x, acc[0][1]); acc[0][1] = fmaf(a0.y, b1.y, acc[0][1]);
      acc[0][1] = fmaf(a0.z, b1.z, acc[0][1]); acc[0][1] = fmaf(a0.w, b1.w, acc[0][1]);
      acc[0][2] = fmaf(a0.x, b2.x, acc[0][2]); acc[0][2] = fmaf(a0.y, b2.y, acc[0][2]);
      acc[0][2] = fmaf(a0.z, b2.z, acc[0][2]); acc[0][2] = fmaf(a0.w, b2.w, acc[0][2]);
      acc[0][3] = fmaf(a0.x, b3.x, acc[0][3]); acc[0][3] = fmaf(a0.y, b3.y, acc[0][3]);
      acc[0][3] = fmaf(a0.z, b3.z, acc[0][3]); acc[0][3] = fmaf(a0.w, b3.w, acc[0][3]);
      acc[1][0] = fmaf(a1.x, b0.x, acc[1][0]); acc[1][0] = fmaf(a1.y, b0.y, acc[1][0]);
      acc[1][0] = fmaf(a1.z, b0.z, acc[1][0]); acc[1][0] = fmaf(a1.w, b0.w, acc[1][0]);
      acc[1][1] = fmaf(a1.x, b1.x, acc[1][1]); acc[1][1] = fmaf(a1.y, b1.y, acc[1][1]);
      acc[1][1] = fmaf(a1.z, b1.z, acc[1][1]); acc[1][1] = fmaf(a1.w, b1.w, acc[1][1]);
      acc[1][2] = fmaf(a1.x, b2.x, acc[1][2]); acc[1][2] = fmaf(a1.y, b2.y, acc[1][2]);
      acc[1][2] = fmaf(a1.z, b2.z, acc[1][2]); acc[1][2] = fmaf(a1.w, b2.w, acc[1][2]);
      acc[1][3] = fmaf(a1.x, b3.x, acc[1][3]); acc[1][3] = fmaf(a1.y, b3.y, acc[1][3]);
      acc[1][3] = fmaf(a1.z, b3.z, acc[1][3]); acc[1][3] = fmaf(a1.w, b3.w, acc[1][3]);
    }
    __syncthreads();
  }
  const float4 o0 = make_float4(acc[0][0], acc[0][1], acc[0][2], acc[0][3]);
  const float4 o1 = make_float4(acc[1][0], acc[1][1], acc[1][2], acc[1][3]);
  float* pbase = part + (size_t)kc * TE;
  *reinterpret_cast<float4*>(&pbase[(size_t)(row0 + rr) * E_EXP + cc * 4]) = o0;
  *reinterpret_cast<float4*>(&pbase[(size_t)(row0 + rr + 16) * E_EXP + cc * 4]) = o1;
}

// ---------------- K2: per-row softmax + top1 + gumbel-top2 ----------------
// grid 256 x 256 threads (4 waves). Sums the 4 split-K partials in fixed order.
__global__ __launch_bounds__(256) void k_gate(const float* __restrict__ part,
                                              const float* __restrict__ gumbel,
                                              float* __restrict__ colpart,
                                              int* __restrict__ idx1,
                                              int* __restrict__ idx2,
                                              float* __restrict__ g1v,
                                              float* __restrict__ g2v) {
  const int lane = threadIdx.x & 63;
  const int wave = threadIdx.x >> 6;
  const int gwave = blockIdx.x * 4 + wave;  // 0..1023
  float colacc = 0.f;
  for (int i = 0; i < 8; ++i) {
    const int t = gwave + i * 1024;
    const int o = t * 64 + lane;
    const float L = (part[o] + part[TE + o]) + (part[2 * TE + o] + part[3 * TE + o]);
    // row max
    float m = L;
#pragma unroll
    for (int off = 32; off; off >>= 1) m = fmaxf(m, __shfl_xor(m, off));
    const float e = expf(L - m);
    float s = e;
#pragma unroll
    for (int off = 32; off; off >>= 1) s += __shfl_xor(s, off);
    const float g = e / s;
    colacc += g;
    // argmax1 over gates, first-max semantics (ties -> lowest index)
    float v = g; int ix = lane;
#pragma unroll
    for (int off = 32; off; off >>= 1) {
      float v2 = __shfl_xor(v, off); int i2 = __shfl_xor(ix, off);
      if (v2 > v || (v2 == v && i2 < ix)) { v = v2; ix = i2; }
    }
    const int i1 = ix;
    const float gate1 = __shfl(g, i1);
    // argmax2 over noised logits, expert i1 masked out
    float nz = L + gumbel[o];
    if (lane == i1) nz = -INFINITY;
    float v2v = nz; int ix2 = lane;
#pragma unroll
    for (int off = 32; off; off >>= 1) {
      float v2 = __shfl_xor(v2v, off); int j2 = __shfl_xor(ix2, off);
      if (v2 > v2v || (v2 == v2v && j2 < ix2)) { v2v = v2; ix2 = j2; }
    }
    const int i2x = ix2;
    const float gate2 = __shfl(g, i2x);
    if (lane == 0) { idx1[t] = i1; idx2[t] = i2x; g1v[t] = gate1; g2v[t] = gate2; }
  }
  __shared__ float cs[4][64];
  cs[wave][lane] = colacc;
  __syncthreads();
  if (wave == 0) {
    float ssum = cs[0][lane] + cs[1][lane] + cs[2][lane] + cs[3][lane];
    colpart[blockIdx.x * 64 + lane] = ssum;
  }
}

// ---------------- K3: local ranks + chunk histograms ----------------
__global__ __launch_bounds__(256) void k_rank(const int* __restrict__ idx1,
                                              const int* __restrict__ idx2,
                                              int* __restrict__ rank1,
                                              int* __restrict__ rank2,
                                              int* __restrict__ hist1,
                                              int* __restrict__ hist2) {
  __shared__ int s1[256], s2[256];
  __shared__ int h1[64], h2[64];
  const int tid = threadIdx.x;
  const int base = blockIdx.x * 256;
  if (tid < 64) { h1[tid] = 0; h2[tid] = 0; }
  s1[tid] = idx1[base + tid];
  s2[tid] = idx2[base + tid];
  __syncthreads();
  const int my1 = s1[tid], my2 = s2[tid];
  int r1 = 0, r2 = 0;
  for (int j = 0; j < 256; ++j) {
    r1 += (j < tid && s1[j] == my1);
    r2 += (j < tid && s2[j] == my2);
  }
  atomicAdd(&h1[my1], 1);
  atomicAdd(&h2[my2], 1);
  rank1[base + tid] = r1;
  rank2[base + tid] = r2;
  __syncthreads();
  if (tid < 64) {
    hist1[blockIdx.x * 64 + tid] = h1[tid];
    hist2[blockIdx.x * 64 + tid] = h2[tid];
  }
}

// ---------------- K4: chunk-prefix offsets + l_aux ----------------
__global__ __launch_bounds__(64) void k_prefix(const int* __restrict__ hist1,
                                               const int* __restrict__ hist2,
                                               const float* __restrict__ colpart,
                                               int* __restrict__ offs1,
                                               int* __restrict__ offs2,
                                               float* __restrict__ dout) {
  const int e = threadIdx.x;
  int run = 0;
  for (int c = 0; c < NCHUNK; ++c) { offs1[c * 64 + e] = run; run += hist1[c * 64 + e]; }
  const int total1 = run;
  int run2 = total1;  // locations2 offset includes sum(mask1, axis=0)
  for (int c = 0; c < NCHUNK; ++c) { offs2[c * 64 + e] = run2; run2 += hist2[c * 64 + e]; }
  float csum = 0.f;
  for (int b = 0; b < 256; ++b) csum += colpart[b * 64 + e];
  const float me = csum / (float)T_TOK;
  const float ce = (float)total1 / (float)T_TOK;
  float val = me * ce;
#pragma unroll
  for (int o = 32; o; o >>= 1) val += __shfl_xor(val, o);
  if (e == 0) dout[0] = val * (float)E_EXP;  // mean(me*ce)*E*E = sum*E
}

// ---------------- K5: sparse scatter of combine weights + dispatch ----------------
__global__ __launch_bounds__(256) void k_scatter(const int* __restrict__ idx1,
                                                 const int* __restrict__ idx2,
                                                 const float* __restrict__ g1v,
                                                 const float* __restrict__ g2v,
                                                 const int* __restrict__ rank1,
                                                 const int* __restrict__ rank2,
                                                 const int* __restrict__ offs1,
                                                 const int* __restrict__ offs2,
                                                 float* __restrict__ dout) {
  const int t = blockIdx.x * 256 + threadIdx.x;
  const int c = t >> 8;
  const int e1 = idx1[t], e2 = idx2[t];
  const int loc1 = offs1[c * 64 + e1] + rank1[t];
  const int loc2 = offs2[c * 64 + e2] + rank2[t];
  const bool k1 = loc1 < CAP;
  const bool k2 = loc2 < CAP;
  const float a = k1 ? g1v[t] : 0.f;
  const float b = k2 ? g2v[t] : 0.f;
  const float denom = fmaxf(a + b, 1.1920929e-7f);  // FLT_EPSILON
  if (k1) {
    const long long o = 1LL + ((long long)t * 64 + e1) * 256 + loc1;
    dout[o] = a / denom;
    dout[o + TEC] = 1.0f;
  }
  if (k2) {
    const long long o = 1LL + ((long long)t * 64 + e2) * 256 + loc2;
    dout[o] = b / denom;
    dout[o + TEC] = 1.0f;
  }
}

extern "C" void kernel_launch(void* const* d_in, const int* in_sizes, int n_in,
                              void* d_out, int out_size, void* d_ws, size_t ws_size,
                              hipStream_t stream) {
  const float* x = (const float*)d_in[0];
  const float* wg = (const float*)d_in[1];
  const float* gumbel = (const float*)d_in[2];
  float* dout = (float*)d_out;

  // workspace layout (aligned chunks)
  char* p = (char*)d_ws;
  float* part = (float*)p;              p += (size_t)KSPLIT * TE * 4;     // 8 MB
  float* colpart = (float*)p;           p += 256 * 64 * 4;                // 64 KB
  float* g1v = (float*)p;               p += T_TOK * 4;
  float* g2v = (float*)p;               p += T_TOK * 4;
  int* idx1 = (int*)p;                  p += T_TOK * 4;
  int* idx2 = (int*)p;                  p += T_TOK * 4;
  int* rank1 = (int*)p;                 p += T_TOK * 4;
  int* rank2 = (int*)p;                 p += T_TOK * 4;
  int* hist1 = (int*)p;                 p += NCHUNK * 64 * 4;
  int* hist2 = (int*)p;                 p += NCHUNK * 64 * 4;
  int* offs1 = (int*)p;                 p += NCHUNK * 64 * 4;
  int* offs2 = (int*)p;                 p += NCHUNK * 64 * 4;

  // zero-fill the (sparse) 1.07 GB output — the structural floor of this op
  hipMemsetAsync(d_out, 0, (size_t)out_size * sizeof(float), stream);

  k_gemm<<<(T_TOK / 32) * KSPLIT, 256, 0, stream>>>(x, wg, part);
  k_gate<<<256, 256, 0, stream>>>(part, gumbel, colpart, idx1, idx2, g1v, g2v);
  k_rank<<<NCHUNK, 256, 0, stream>>>(idx1, idx2, rank1, rank2, hist1, hist2);
  k_prefix<<<1, 64, 0, stream>>>(hist1, hist2, colpart, offs1, offs2, dout);
  k_scatter<<<NCHUNK, 256, 0, stream>>>(idx1, idx2, g1v, g2v, rank1, rank2,
                                        offs1, offs2, dout);
}